// Round 2
// baseline (2841.515 us; speedup 1.0000x reference)
//
#include <hip/hip_runtime.h>

#define HID  64
#define SEQT 1024

typedef float v2f __attribute__((ext_vector_type(2)));
typedef float v4f __attribute__((ext_vector_type(4)));

__device__ __forceinline__ float rcpf(float x) { return __builtin_amdgcn_rcpf(x); }
__device__ __forceinline__ float sigm(float x) { return rcpf(1.0f + __expf(-x)); }
__device__ __forceinline__ float tanh_fast(float x) {
    // 1 - 2/(e^{2x}+1); correct saturation at +-inf
    return 1.0f - 2.0f * rcpf(__expf(2.0f * x) + 1.0f);
}
// v_pk_fma_f32 (dual-issue fp32) via vector fma; exact IEEE fp32 fma semantics.
__device__ __forceinline__ v2f pkfma(v2f a, v2f b, v2f c) {
    return __builtin_elementwise_fma(a, b, c);
}

// One block = one batch element. 512 threads = 8 waves.
// Waves 0-3: layer-0 gates for step k.  Waves 4-7: layer-1 gates for step k-1
// (software pipeline; h1/h2 double-buffered in LDS). Wave w and w+4 share a
// SIMD -> one light (32 pk-FMA) + one heavy (64 pk-FMA) wave per SIMD.
// Weights register-resident: L0 64 floats, L1 128 floats per lane -> fits the
// arch VGPR file (no AGPR spill round-trips, the round-1 tax).
__global__ __launch_bounds__(512, 2)
void lstm2_pipe(const float* __restrict__ x,
                const float* __restrict__ W_ih0, const float* __restrict__ W_hh0,
                const float* __restrict__ b_ih0, const float* __restrict__ b_hh0,
                const float* __restrict__ W_ih1, const float* __restrict__ W_hh1,
                const float* __restrict__ b_ih1, const float* __restrict__ b_hh1,
                const float* __restrict__ fc1_w, const float* __restrict__ fc1_b,
                const float* __restrict__ fc2_w, const float* __restrict__ fc2_b,
                float* __restrict__ out, int batch)
{
    const int b   = blockIdx.x;
    if (b >= batch) return;
    const int tid = threadIdx.x;
    const int w   = tid >> 6;        // wave id 0..7
    const int j   = tid & 63;        // lane
    const bool L1 = (w >= 4);
    const int g     = ((w & 3) << 6) | j;   // gate index within the layer
    const int gtype = w & 3;                // 0:i 1:f 2:g(tanh) 3:o

    __shared__ float gates0[256];
    __shared__ float gates1[256];
    __shared__ __align__(16) float h1buf[2][HID];
    __shared__ __align__(16) float h2buf[2][HID];

    // ---- register-resident weight rows (v2f pairs for pk_fma) ----
    v2f wA[32], wB[32];
    {
        const v2f* rowA = (const v2f*)((L1 ? W_ih1 : W_hh0) + g * HID);
        #pragma unroll
        for (int q = 0; q < 32; ++q) wA[q] = rowA[q];
        // L0 waves load a dummy (their own W_hh0 row again) — never used.
        const v2f* rowB = (const v2f*)((L1 ? W_hh1 : W_hh0) + g * HID);
        #pragma unroll
        for (int q = 0; q < 32; ++q) wB[q] = rowB[q];
    }
    const float wih0g = L1 ? 0.0f : W_ih0[g];            // INPUT_SIZE == 1
    const float bias  = L1 ? (b_ih1[g] + b_hh1[g]) : (b_ih0[g] + b_hh0[g]);

    float c = 0.0f;                  // c1 for wave 0 lanes, c2 for wave 4 lanes
    if (tid < HID) {
        h1buf[0][tid] = 0.0f; h1buf[1][tid] = 0.0f;
        h2buf[0][tid] = 0.0f; h2buf[1][tid] = 0.0f;
    }
    __syncthreads();

    const float* __restrict__ xrow = x + (size_t)b * SEQT;

    // iter k: L0 produces h1(k) [k<SEQT]; L1 produces h2(k-1) [k>=1].
    // read buffer index k&1, write buffer index (k&1)^1 for both h1 and h2.
    #pragma unroll 1
    for (int k = 0; k <= SEQT; ++k) {
        const int cur = k & 1;
        const int nxt = cur ^ 1;

        // ---------------- phase A: gate dots ----------------
        if (!L1) {
            if (k < SEQT) {
                const float xt = xrow[k];
                const v4f* hv = (const v4f*)h1buf[cur];
                v2f a0 = {0.f, 0.f}, a1 = {0.f, 0.f};
                #pragma unroll
                for (int q = 0; q < 16; ++q) {
                    v4f h = hv[q];                       // broadcast ds_read_b128
                    v2f lo = {h.x, h.y}, hi = {h.z, h.w};
                    a0 = pkfma(lo, wA[2*q],     a0);
                    a1 = pkfma(hi, wA[2*q + 1], a1);
                }
                float pre = fmaf(xt, wih0g, bias) + ((a0.x + a1.x) + (a0.y + a1.y));
                gates0[g] = (gtype == 2) ? tanh_fast(pre) : sigm(pre);
            }
        } else {
            if (k >= 1) {
                const v4f* uv = (const v4f*)h1buf[cur];  // h1(k-1)
                const v4f* vv = (const v4f*)h2buf[cur];  // h2(k-2)
                v2f a0 = {0.f,0.f}, a1 = {0.f,0.f}, a2 = {0.f,0.f}, a3 = {0.f,0.f};
                #pragma unroll
                for (int q = 0; q < 16; ++q) {
                    v4f u = uv[q], v = vv[q];
                    v2f ulo = {u.x, u.y}, uhi = {u.z, u.w};
                    v2f vlo = {v.x, v.y}, vhi = {v.z, v.w};
                    a0 = pkfma(ulo, wA[2*q],     a0);
                    a1 = pkfma(uhi, wA[2*q + 1], a1);
                    a2 = pkfma(vlo, wB[2*q],     a2);
                    a3 = pkfma(vhi, wB[2*q + 1], a3);
                }
                float pre = bias + ((a0.x + a1.x) + (a2.x + a3.x))
                                 + ((a0.y + a1.y) + (a2.y + a3.y));
                gates1[g] = (gtype == 2) ? tanh_fast(pre) : sigm(pre);
            }
        }
        __syncthreads();

        // ---------------- phase B: cell updates ----------------
        if (w == 0 && k < SEQT) {
            float i0 = gates0[j], f0 = gates0[64 + j];
            float g0 = gates0[128 + j], o0 = gates0[192 + j];
            c = fmaf(f0, c, i0 * g0);
            h1buf[nxt][j] = o0 * tanh_fast(c);
        }
        if (w == 4 && k >= 1) {
            float i1 = gates1[j], f1 = gates1[64 + j];
            float g1 = gates1[128 + j], o1 = gates1[192 + j];
            c = fmaf(f1, c, i1 * g1);
            h2buf[nxt][j] = o1 * tanh_fast(c);
        }
        __syncthreads();
    }

    // ---- FC head: h2(SEQT-1) sits in h2buf[(SEQT+1)&1] ----
    if (w == 4) {
        const float* h2last = h2buf[(SEQT + 1) & 1];
        float z = 0.0f;
        if (j < 32) {
            float acc = fc1_b[j];
            #pragma unroll
            for (int kk = 0; kk < HID; ++kk)
                acc = fmaf(h2last[kk], fc1_w[j * HID + kk], acc);
            z = fmaxf(acc, 0.0f) * fc2_w[j];
        }
        #pragma unroll
        for (int off = 32; off > 0; off >>= 1) z += __shfl_xor(z, off);
        if (j == 0) out[b] = z + fc2_b[0];
    }
}

extern "C" void kernel_launch(void* const* d_in, const int* in_sizes, int n_in,
                              void* d_out, int out_size, void* d_ws, size_t ws_size,
                              hipStream_t stream) {
    const float* x     = (const float*)d_in[0];
    const float* W_ih0 = (const float*)d_in[1];
    const float* W_hh0 = (const float*)d_in[2];
    const float* b_ih0 = (const float*)d_in[3];
    const float* b_hh0 = (const float*)d_in[4];
    const float* W_ih1 = (const float*)d_in[5];
    const float* W_hh1 = (const float*)d_in[6];
    const float* b_ih1 = (const float*)d_in[7];
    const float* b_hh1 = (const float*)d_in[8];
    const float* fc1_w = (const float*)d_in[9];
    const float* fc1_b = (const float*)d_in[10];
    const float* fc2_w = (const float*)d_in[11];
    const float* fc2_b = (const float*)d_in[12];
    float* out = (float*)d_out;

    const int batch = in_sizes[0] / SEQT;   // 1024
    dim3 grid(batch), block(512);
    hipLaunchKernelGGL(lstm2_pipe, grid, block, 0, stream,
                       x, W_ih0, W_hh0, b_ih0, b_hh0,
                       W_ih1, W_hh1, b_ih1, b_hh1,
                       fc1_w, fc1_b, fc2_w, fc2_b, out, batch);
}